// Round 10
// baseline (56.687 us; speedup 1.0000x reference)
//
#include <hip/hip_runtime.h>

#define IN_DIM   256
#define OUT_DIM  128
#define IN_SEQ   512
#define OUT_SEQ  512
#define NUM_BASIS 16
#define LN_EPS   1e-5f

__device__ __forceinline__ float cosrev(float x) {
  // cos(2*pi*x): v_fract then v_cos (revolutions semantics)
  return __builtin_amdgcn_cosf(__builtin_amdgcn_fractf(x));
}

// ---------------------------------------------------------------------------
// Kernel 1: Z = x @ M.T (one block per k), LayerNorm.
// Writes ZnT[j][k] (normalized, transposed -> k_pos reads coalesced by k),
// V[k][i] = pre-LN z (residual base k_pos adds onto), and the pairs table
// pairs[e] = {P[e], 1/(e+2)} (p(i,j,g) = flat_index + 2), hoisting rcp out
// of k_pos's inner loop.
// ---------------------------------------------------------------------------
__global__ __launch_bounds__(256) void k_prep(const float* __restrict__ x,
                                              const float* __restrict__ M,
                                              const float* __restrict__ P,
                                              const float* __restrict__ gamma,
                                              const float* __restrict__ beta,
                                              float* __restrict__ ZnT,
                                              float* __restrict__ V,
                                              float2* __restrict__ pairs) {
  const int k = blockIdx.x;
  const int t = threadIdx.x;
  __shared__ __align__(16) float xk[IN_DIM];
  __shared__ float red[256];
  __shared__ float stats[8];

  // pairs table: 2 entries per thread, fully coalesced
  {
    const int e0 = k * 512 + t;
    const int e1 = e0 + 256;
    pairs[e0] = make_float2(P[e0], __builtin_amdgcn_rcpf((float)(e0 + 2)));
    pairs[e1] = make_float2(P[e1], __builtin_amdgcn_rcpf((float)(e1 + 2)));
  }

  xk[t] = x[k * IN_DIM + t];
  __syncthreads();

  const int j = t & 127;
  const int h = t >> 7;  // which half of the 256-dim input
  const float4* __restrict__ M4 =
      reinterpret_cast<const float4*>(M + j * IN_DIM + h * 128);
  const float4* __restrict__ x4 = reinterpret_cast<const float4*>(xk + h * 128);
  float acc = 0.f;
#pragma unroll 8
  for (int c = 0; c < 32; ++c) {
    float4 m = M4[c];
    float4 xv = x4[c];
    acc = fmaf(m.x, xv.x, acc);
    acc = fmaf(m.y, xv.y, acc);
    acc = fmaf(m.z, xv.z, acc);
    acc = fmaf(m.w, xv.w, acc);
  }
  red[t] = acc;
  __syncthreads();

  float z = 0.f;
  if (t < 128) z = red[t] + red[t + 128];

  float s1 = (t < 128) ? z : 0.f;
  float s2 = (t < 128) ? z * z : 0.f;
#pragma unroll
  for (int m = 1; m < 64; m <<= 1) {
    s1 += __shfl_xor(s1, m);
    s2 += __shfl_xor(s2, m);
  }
  const int w = t >> 6;
  if ((t & 63) == 0) {
    stats[w] = s1;
    stats[4 + w] = s2;
  }
  __syncthreads();
  const float mu  = (stats[0] + stats[1] + stats[2] + stats[3]) * (1.f / 128.f);
  const float msq = (stats[4] + stats[5] + stats[6] + stats[7]) * (1.f / 128.f);
  const float rs  = rsqrtf(msq - mu * mu + LN_EPS);

  if (t < 128) {
    float zn = (z - mu) * rs * gamma[t] + beta[t];
    ZnT[t * IN_SEQ + k] = zn;      // transposed (scattered 4B, tiny total)
    V[k * OUT_DIM + t]  = z;       // coalesced; residual base for k_pos
  }
}

// ---------------------------------------------------------------------------
// Kernel 2: position transform, direct cos, k-in-lane, NO atomics.
// 512 threads (8 waves): thread = (k-local 0..63, g-pair 0..7), 2 g per j.
// Grid (8 k-slices, 128 i) = 1024 blocks -> 4 blocks x 512 thr = 2048
// thr/CU = 32 waves/CU (100% cap; VGPR=12, LDS 2KB can't block it).
// Round 9 ran 4 waves/block at 27-31% occupancy, VALUBusy ~40% ->
// latency-bound with idle issue slots; doubling resident waves is the
// cheapest 2x on issue utilization. gp forced wave-uniform via
// readfirstlane so pair loads stay scalar. Single-writer += on V.
// ---------------------------------------------------------------------------
__global__ __launch_bounds__(512) void k_pos(const float2* __restrict__ pairs,
                                             const float* __restrict__ ZnT,
                                             float* __restrict__ V) {
  const int ks = blockIdx.x;   // 0..7
  const int i  = blockIdx.y;   // 0..127
  const int t  = threadIdx.x;  // 0..511
  const int kl = t & 63;
  const int gp = __builtin_amdgcn_readfirstlane(t >> 6);  // wave-uniform 0..7
  const int k  = ks * 64 + kl;
  const float kf = (float)k;

  const float2* __restrict__ pj =
      pairs + (size_t)i * (OUT_DIM * NUM_BASIS) + gp * 2;
  const float* __restrict__ zj = ZnT + k;

  float acc = 0.f;
#pragma unroll 8
  for (int j = 0; j < OUT_DIM; ++j) {
    const float z = zj[j * IN_SEQ];             // coalesced 256B/wave, L1/L2
    const float2 q0 = pj[j * NUM_BASIS + 0];    // uniform -> s_load_dwordx4
    const float2 q1 = pj[j * NUM_BASIS + 1];
    float s = q0.x * cosrev(kf * q0.y);
    s = fmaf(q1.x, cosrev(kf * q1.y), s);
    acc = fmaf(z, s, acc);
  }

  __shared__ float red[8][64];
  red[gp][kl] = acc;
  __syncthreads();
  if (t < 64) {
    const int kk = ks * 64 + t;
    const float sum = ((red[0][t] + red[1][t]) + (red[2][t] + red[3][t])) +
                      ((red[4][t] + red[5][t]) + (red[6][t] + red[7][t]));
    V[(size_t)kk * OUT_DIM + i] += sum;
  }
}

// ---------------------------------------------------------------------------
// Kernel 3: out[s,:] = sum_k L[k,s] * V[k,:]. 2 s-rows per block. L loads
// block-uniform -> s_loads; V rows coalesced. Direct store, no atomics.
// ---------------------------------------------------------------------------
__global__ __launch_bounds__(256) void k_seq(const float* __restrict__ L,
                                             const float* __restrict__ V,
                                             float* __restrict__ out) {
  const int s0 = blockIdx.x * 2;
  const int t  = threadIdx.x;
  const int i  = t & 127;
  const int q  = t >> 7;            // k-half
  __shared__ float red[2][2][OUT_DIM];   // [q][s-local][i]

  const int kb = q * 256;
  float a0 = 0.f, a1 = 0.f;
#pragma unroll 8
  for (int kk = 0; kk < 256; ++kk) {
    const int k = kb + kk;
    const float v = V[(size_t)k * OUT_DIM + i];          // coalesced
    a0 = fmaf(L[(size_t)k * OUT_SEQ + s0], v, a0);       // uniform s_loads
    a1 = fmaf(L[(size_t)k * OUT_SEQ + s0 + 1], v, a1);
  }
  red[q][0][i] = a0;
  red[q][1][i] = a1;
  __syncthreads();

  // thread (q,i) writes out[s0+q][i]
  out[(size_t)(s0 + q) * OUT_DIM + i] = red[0][q][i] + red[1][q][i];
}

extern "C" void kernel_launch(void* const* d_in, const int* in_sizes, int n_in,
                              void* d_out, int out_size, void* d_ws, size_t ws_size,
                              hipStream_t stream) {
  const float* x      = (const float*)d_in[0];
  const float* M      = (const float*)d_in[1];
  const float* P      = (const float*)d_in[2];
  const float* Linker = (const float*)d_in[3];
  const float* gamma  = (const float*)d_in[4];
  const float* beta   = (const float*)d_in[5];
  // d_in[6] = periods (recomputed inline: p = flat(i,j,g) + 2, exact in f32)
  float* out = (float*)d_out;

  float* ws  = (float*)d_ws;
  float* ZnT   = ws;                          // [128 j][512 k]
  float* V     = ws + OUT_DIM * IN_SEQ;       // [512 k][128 i], init = pre-LN Z
  float2* pairs = (float2*)(ws + 2 * OUT_DIM * IN_SEQ);  // [i][j][g] {P, 1/p}

  k_prep<<<dim3(IN_SEQ), dim3(256), 0, stream>>>(x, M, P, gamma, beta, ZnT, V, pairs);
  k_pos<<<dim3(8, OUT_DIM), dim3(512), 0, stream>>>(pairs, ZnT, V);
  k_seq<<<dim3(OUT_SEQ / 2), dim3(256), 0, stream>>>(Linker, V, out);
}

// Round 11
// 45.436 us; speedup vs baseline: 1.2476x; 1.2476x over previous
//
#include <hip/hip_runtime.h>

#define IN_DIM   256
#define OUT_DIM  128
#define IN_SEQ   512
#define OUT_SEQ  512
#define NUM_BASIS 16
#define LN_EPS   1e-5f
#define KC       16          // k-chunk per thread (16 accumulators)

__device__ __forceinline__ float cosrev(float x) {
  // cos(2*pi*x): v_fract then v_cos (revolutions semantics)
  return __builtin_amdgcn_cosf(__builtin_amdgcn_fractf(x));
}

// ---------------------------------------------------------------------------
// Kernel 1: Z = x @ M.T (one block per k), LayerNorm.
// Writes ZnT[j][k] (transposed -> k_cheb s_loads 64B rows), V[k][i] = pre-LN z
// (residual base k_cheb atomically adds onto), and Pt[jg][i] = P[i][jg]
// (transpose so k_cheb's per-lane Pw load is coalesced; one-time 1MB).
// ---------------------------------------------------------------------------
__global__ __launch_bounds__(256) void k_prep(const float* __restrict__ x,
                                              const float* __restrict__ M,
                                              const float* __restrict__ P,
                                              const float* __restrict__ gamma,
                                              const float* __restrict__ beta,
                                              float* __restrict__ ZnT,
                                              float* __restrict__ V,
                                              float* __restrict__ Pt) {
  const int k = blockIdx.x;
  const int t = threadIdx.x;
  __shared__ __align__(16) float xk[IN_DIM];
  __shared__ float red[256];
  __shared__ float stats[8];

  // P transpose slice: block k covers e in [k*512, k*512+512)
  {
    const int e0 = k * 512 + t;
    const int e1 = e0 + 256;
    Pt[(e0 & 2047) * OUT_DIM + (e0 >> 11)] = P[e0];
    Pt[(e1 & 2047) * OUT_DIM + (e1 >> 11)] = P[e1];
  }

  xk[t] = x[k * IN_DIM + t];
  __syncthreads();

  const int j = t & 127;
  const int h = t >> 7;  // which half of the 256-dim input
  const float4* __restrict__ M4 =
      reinterpret_cast<const float4*>(M + j * IN_DIM + h * 128);
  const float4* __restrict__ x4 = reinterpret_cast<const float4*>(xk + h * 128);
  float acc = 0.f;
#pragma unroll 8
  for (int c = 0; c < 32; ++c) {
    float4 m = M4[c];
    float4 xv = x4[c];
    acc = fmaf(m.x, xv.x, acc);
    acc = fmaf(m.y, xv.y, acc);
    acc = fmaf(m.z, xv.z, acc);
    acc = fmaf(m.w, xv.w, acc);
  }
  red[t] = acc;
  __syncthreads();

  float z = 0.f;
  if (t < 128) z = red[t] + red[t + 128];

  float s1 = (t < 128) ? z : 0.f;
  float s2 = (t < 128) ? z * z : 0.f;
#pragma unroll
  for (int m = 1; m < 64; m <<= 1) {
    s1 += __shfl_xor(s1, m);
    s2 += __shfl_xor(s2, m);
  }
  const int w = t >> 6;
  if ((t & 63) == 0) {
    stats[w] = s1;
    stats[4 + w] = s2;
  }
  __syncthreads();
  const float mu  = (stats[0] + stats[1] + stats[2] + stats[3]) * (1.f / 128.f);
  const float msq = (stats[4] + stats[5] + stats[6] + stats[7]) * (1.f / 128.f);
  const float rs  = rsqrtf(msq - mu * mu + LN_EPS);

  if (t < 128) {
    float zn = (z - mu) * rs * gamma[t] + beta[t];
    ZnT[t * IN_SEQ + k] = zn;      // transposed (scattered 4B, tiny total)
    V[k * OUT_DIM + t]  = z;       // coalesced; residual base for k_cheb
  }
}

// ---------------------------------------------------------------------------
// Kernel 2: position transform via Chebyshev recurrence, i-IN-LANE layout.
// T[k,i] = sum_{j,g} Zn[k,j] * P[i,j,g] * cos(2*pi*k/p), p = i*2048+j*16+g+2.
// c'(k) = P*cos(k*theta) obeys c'(k+1) = 2cos(theta)*c'(k) - c'(k-1)
// (linearity lets P fold into the init) -> 2 FMA per element instead of a
// ~16-cyc wave64 v_cos (rounds 8-10: direct-cos floor ~20us, trans-pipe).
// Layout kills rounds 2-7's diseases: reduction over (j,g) is THREAD-PRIVATE
// (i in lane), z-chunk is wave-uniform (s_load_dwordx16 from ZnT row), Pw is
// a coalesced lane load from Pt, state per stream = {tc,c0,c1} = 3 regs,
// acc[KC] static-indexed in a fully-unrolled k-loop. #pragma unroll 2 on the
// g-loop caps live streams (16x interleave would blow to ~100 VGPR).
// Grid: (32 k-chunks, 16 j-splits); 256 thr = 128 i x 2 jsub (4 j each).
// Transcendental count: 3 per (j,g)-stream = 8.4M lane-cos vs 134M direct.
// Epilogue: LDS-reduce jsub pair, 16 atomicAdd per i-thread onto V
// (1M atomics total, 16 contenders/address, ~3us).
// ---------------------------------------------------------------------------
__global__ __launch_bounds__(256) void k_cheb(const float* __restrict__ Pt,
                                              const float* __restrict__ ZnT,
                                              float* __restrict__ V) {
  const int chunk = blockIdx.x;    // 0..31 (16 k each)
  const int jsp   = blockIdx.y;    // 0..15 (8 j each)
  const int t     = threadIdx.x;
  const int i     = t & 127;
  const int jsub  = __builtin_amdgcn_readfirstlane(t >> 7);  // wave-uniform 0/1
  const int k0    = chunk * KC;
  const float fk0  = (float)k0;
  const float fkm1 = (float)(k0 - 1);   // k=-1 ok: cos even, fract handles neg
  const int jbase = jsp * 8 + jsub * 4;

  float acc[KC];
#pragma unroll
  for (int c = 0; c < KC; ++c) acc[c] = 0.f;

  for (int jj = 0; jj < 4; ++jj) {
    const int j = jbase + jj;
    const float* __restrict__ zp = ZnT + j * IN_SEQ + k0;   // wave-uniform
    float z[KC];
#pragma unroll
    for (int c = 0; c < KC; ++c) z[c] = zp[c];              // -> s_loads
    const float* __restrict__ ptj = Pt + (size_t)(j * NUM_BASIS) * OUT_DIM + i;
    const int pbase = i * 2048 + j * 16 + 2;
#pragma unroll 2
    for (int g = 0; g < NUM_BASIS; ++g) {
      const float Pw   = ptj[(size_t)g * OUT_DIM];          // coalesced lane load
      const float pinv = __builtin_amdgcn_rcpf((float)(pbase + g));
      const float tc   = 2.0f * __builtin_amdgcn_cosf(pinv);  // pinv<=0.5: no fract
      float c0 = Pw * cosrev(fkm1 * pinv);
      float c1 = Pw * cosrev(fk0 * pinv);
#pragma unroll
      for (int c = 0; c < KC; ++c) {
        acc[c] = fmaf(c1, z[c], acc[c]);          // dot (z is scalar operand)
        const float cn = fmaf(tc, c1, -c0);       // advance
        c0 = c1;
        c1 = cn;
      }
    }
  }

  // combine the two jsub partials, then atomically add onto V
  __shared__ float red[KC][128];
  if (jsub == 1) {
#pragma unroll
    for (int c = 0; c < KC; ++c) red[c][i] = acc[c];
  }
  __syncthreads();
  if (jsub == 0) {
#pragma unroll
    for (int c = 0; c < KC; ++c) {
      atomicAdd(&V[(size_t)(k0 + c) * OUT_DIM + i], acc[c] + red[c][i]);
    }
  }
}

// ---------------------------------------------------------------------------
// Kernel 3: out[s,:] = sum_k L[k,s] * V[k,:]. 2 s-rows per block. L loads
// block-uniform -> s_loads; V rows coalesced. Direct store, no atomics.
// ---------------------------------------------------------------------------
__global__ __launch_bounds__(256) void k_seq(const float* __restrict__ L,
                                             const float* __restrict__ V,
                                             float* __restrict__ out) {
  const int s0 = blockIdx.x * 2;
  const int t  = threadIdx.x;
  const int i  = t & 127;
  const int q  = t >> 7;            // k-half
  __shared__ float red[2][2][OUT_DIM];   // [q][s-local][i]

  const int kb = q * 256;
  float a0 = 0.f, a1 = 0.f;
#pragma unroll 8
  for (int kk = 0; kk < 256; ++kk) {
    const int k = kb + kk;
    const float v = V[(size_t)k * OUT_DIM + i];          // coalesced
    a0 = fmaf(L[(size_t)k * OUT_SEQ + s0], v, a0);       // uniform s_loads
    a1 = fmaf(L[(size_t)k * OUT_SEQ + s0 + 1], v, a1);
  }
  red[q][0][i] = a0;
  red[q][1][i] = a1;
  __syncthreads();

  // thread (q,i) writes out[s0+q][i]
  out[(size_t)(s0 + q) * OUT_DIM + i] = red[0][q][i] + red[1][q][i];
}

extern "C" void kernel_launch(void* const* d_in, const int* in_sizes, int n_in,
                              void* d_out, int out_size, void* d_ws, size_t ws_size,
                              hipStream_t stream) {
  const float* x      = (const float*)d_in[0];
  const float* M      = (const float*)d_in[1];
  const float* P      = (const float*)d_in[2];
  const float* Linker = (const float*)d_in[3];
  const float* gamma  = (const float*)d_in[4];
  const float* beta   = (const float*)d_in[5];
  // d_in[6] = periods (recomputed inline: p = flat(i,j,g) + 2, exact in f32)
  float* out = (float*)d_out;

  float* ws  = (float*)d_ws;
  float* ZnT = ws;                          // [128 j][512 k]
  float* V   = ws + OUT_DIM * IN_SEQ;       // [512 k][128 i], init = pre-LN Z
  float* Pt  = ws + 2 * OUT_DIM * IN_SEQ;   // [2048 jg][128 i] transposed P

  k_prep<<<dim3(IN_SEQ), dim3(256), 0, stream>>>(x, M, P, gamma, beta, ZnT, V, Pt);
  k_cheb<<<dim3(IN_SEQ / KC, 16), dim3(256), 0, stream>>>(Pt, ZnT, V);
  k_seq<<<dim3(OUT_SEQ / 2), dim3(256), 0, stream>>>(Linker, V, out);
}